// Round 8
// baseline (293.501 us; speedup 1.0000x reference)
//
#include <hip/hip_runtime.h>

// CausalLinearRelativeAttention — chunked 3-branch causal linear attention, bf16 MFMA.
// N=4, L=2048, H=8, D=Dv=128, chunk C=128, T=16 chunks, 3 branches (coeff -2 folded into Qb2).
// R8: dropped kbt3. R11: k_kvfeat+p1a fused (k_kvs), L2-hot re-reads confirmed (FETCH 79MB).
// R12: fuse k_qfeat into p3 — qb3 (48MB w + 48MB r) and zintg never touch memory; 5->4 compute
//      dispatches. p3 prologue: wt stage -> proj MFMA -> sin2 (bf16, T0) -> readback (regs) +
//      z-pass (bit-exact k_qfeat order, zl LDS) -> per-branch Qb recompute+stage -> A-frags
//      from LDS -> unchanged Kb/S^T double MFMA + mask + intra + output.

typedef float f32x4 __attribute__((ext_vector_type(4)));
typedef short s16x8 __attribute__((ext_vector_type(8)));
typedef short s16x4 __attribute__((ext_vector_type(4)));
typedef unsigned short u16;

static constexpr int    Ln   = 2048;
static constexpr size_t NHLD = (size_t)32 * 2048 * 128; // per-branch feature elems = 8,388,608
static constexpr size_t KSB  = (size_t)32 * 16 * 128;   // kspre per-branch stride = 65536

__device__ __forceinline__ float b2f(u16 s) {
  union { unsigned u; float f; } x; x.u = ((unsigned)s) << 16; return x.f;
}
__device__ __forceinline__ u16 f2b(float f) {
  union { float f; unsigned u; } x; x.f = f;
  unsigned r = x.u + 0x7fffu + ((x.u >> 16) & 1u);
  return (u16)(r >> 16);
}
__device__ __forceinline__ s16x8 pack8(f32x4 a, f32x4 b) {
  s16x8 r;
  r[0] = (short)f2b(a[0]); r[1] = (short)f2b(a[1]); r[2] = (short)f2b(a[2]); r[3] = (short)f2b(a[3]);
  r[4] = (short)f2b(b[0]); r[5] = (short)f2b(b[1]); r[6] = (short)f2b(b[2]); r[7] = (short)f2b(b[3]);
  return r;
}

// ---------------------------------------------------------------- K0: omega^T (bf16) + column sums
__global__ __launch_bounds__(256) void k_omega(const float* __restrict__ om,
                                               u16* __restrict__ wt, float* __restrict__ osum) {
  __shared__ alignas(16) u16 T[128][136];
  int h = blockIdx.x, t = threadIdx.x;
  for (int idx = t; idx < 128 * 32; idx += 256) {
    int i = idx >> 5, cs = (idx & 31) << 2;
    f32x4 vv = *(const f32x4*)(om + ((size_t)(h * 128 + i)) * 128 + cs);
    T[i][cs + 0] = f2b(vv[0]); T[i][cs + 1] = f2b(vv[1]);
    T[i][cs + 2] = f2b(vv[2]); T[i][cs + 3] = f2b(vv[3]);
  }
  if (t < 128) { // exact fp32 column sums (coalesced per row)
    float acc = 0.f;
    for (int i = 0; i < 128; i++) acc += om[((size_t)(h * 128 + i)) * 128 + t];
    osum[h * 128 + t] = acc;
  }
  __syncthreads();
  { // transposed write: wt[h][j][i] = omega[h][i][j]
    int j = t >> 1, lh = (t & 1) << 6;
    s16x8* dst = (s16x8*)(wt + ((size_t)(h * 128 + j)) * 128 + lh);
    for (int u = 0; u < 8; u++) {
      s16x8 pv;
#pragma unroll
      for (int e = 0; e < 8; e++) pv[e] = (short)T[lh + u * 8 + e][j];
      dst[u] = pv;
    }
  }
}

// ---------------------- K1+P1a fused (k_kvs): one block per (n,h,c), 512 threads.
__global__ __launch_bounds__(512) void k_kvs(const float* __restrict__ kg, const float* __restrict__ vg,
                                             const float* __restrict__ klg, const float* __restrict__ osum,
                                             u16* __restrict__ kb3, u16* __restrict__ vt,
                                             u16* __restrict__ sct, float* __restrict__ ksum) {
  __shared__ union {
    alignas(16) u16 VT[128][128]; // V natural [s][i], swizzled granules (phase A/B)
    alignas(16) u16 KT[128][136]; // Kb^T [i][s] swizzled; then S^T staging (phase C)
  } sm;
  int bid = blockIdx.x, t = threadIdx.x;
  int c = bid & 15, h = (bid >> 4) & 7, n = bid >> 7;
  int l0 = c << 7, nh = (n << 3) + h;
  const float invL = 1.0f / 2048.0f;
  int gcol = t & 31, cs = gcol << 2;          // column quad fixed per thread
  f32x4 osv = *(const f32x4*)(osum + h * 128 + cs);
  // ---- phase A: features + kb3 direct stores + VT build
#pragma unroll
  for (int it = 0; it < 8; it++) {
    int rr = (it << 4) + (t >> 5);            // row in chunk 0..127
    int l = l0 + rr;
    size_t gb = (((size_t)(n * Ln + l) * 8 + h) << 7) + cs;
    f32x4 kv = *(const f32x4*)(kg + gb);
    f32x4 vv = *(const f32x4*)(vg + gb);
    float klv = klg[n * Ln + l];
    float tb = (float)l * invL;
    u16 r0[4], r1[4], r2[4];
#pragma unroll
    for (int e = 0; e < 4; e++) {
      float kf = (kv[e] > 0.f ? kv[e] + 1.f : __expf(kv[e])) * klv;
      float tt = tb * osv[e];
      float s, cc; __sincosf(tt, &s, &cc);
      r0[e] = f2b(kf * cc * cc);
      r1[e] = f2b(kf * s * s);
      r2[e] = f2b(kf * s * cc);
    }
    int gs = (gcol ^ (rr >> 3)) << 2;         // swizzled granule (4 u16)
    *(s16x4*)&sm.VT[rr][gs] = (s16x4){(short)f2b(vv[0]), (short)f2b(vv[1]),
                                      (short)f2b(vv[2]), (short)f2b(vv[3])};
    size_t nb = ((size_t)nh * Ln + l) * 128 + cs;
    *(s16x4*)(kb3 + nb)          = (s16x4){(short)r0[0], (short)r0[1], (short)r0[2], (short)r0[3]};
    *(s16x4*)(kb3 + NHLD + nb)   = (s16x4){(short)r1[0], (short)r1[1], (short)r1[2], (short)r1[3]};
    *(s16x4*)(kb3 + 2*NHLD + nb) = (s16x4){(short)r2[0], (short)r2[1], (short)r2[2], (short)r2[3]};
  }
  __syncthreads();
  // ---- phase B: stream V^T chunk out (contiguous 32KB, full-line writes)
  size_t bv = ((size_t)(nh * 16 + c)) << 14;
  for (int idx = t; idx < 2048; idx += 512) {
    int i = idx >> 4, o = idx & 15;
    int gp = (((i >> 2) ^ o) << 2) + (i & 3);
    s16x8 v1;
#pragma unroll
    for (int u = 0; u < 8; u++) v1[u] = (short)sm.VT[(o << 3) + u][gp];
    *(s16x8*)(vt + bv + (((size_t)i) << 7) + (o << 3)) = v1;
  }
  // ---- phase C: per-branch chunk-S^T (operands L2-hot)
  int lane = t & 63, quad = lane >> 4, nl = lane & 15, w = t >> 6;
  int arow = (w << 4) + nl;                   // j row, 8 waves x 16 = 128
  const u16* vchunk = vt + bv;
  for (int b = 0; b < 3; b++) {
    int bnh = b * 32 + nh;
    const u16* kb = kb3 + (size_t)b * NHLD + ((size_t)nh * Ln + l0) * 128;
    __syncthreads();                          // VT reads / prev sct stream done before KT overwrite
    for (int idx = t; idx < 2048; idx += 512) {
      int s = idx >> 4, io = idx & 15;        // natural row s, i-octet io
      s16x8 v = *(const s16x8*)(kb + (((size_t)s) << 7) + (io << 3)); // L2-hot (own writes)
      int cp = s ^ ((io & 7) << 3);           // swizzled phys column
#pragma unroll
      for (int j = 0; j < 8; j++) sm.KT[(io << 3) + j][cp] = (u16)(short)v[j];
    }
    __syncthreads();
    f32x4 z4 = {0.f, 0.f, 0.f, 0.f};
    f32x4 acc[8];
#pragma unroll
    for (int i = 0; i < 8; i++) acc[i] = z4;
    for (int ks = 0; ks < 4; ks++) {
      int k0 = (ks << 5) + (quad << 3);
      s16x8 av = *(const s16x8*)(vchunk + (((size_t)arow) << 7) + k0); // L2-hot
#pragma unroll
      for (int ct = 0; ct < 8; ct++) {
        int r = (ct << 4) + nl;
        int koff = k0 ^ (((r >> 3) & 7) << 3); // unswizzle octet
        s16x8 bvv = *(const s16x8*)&sm.KT[r][koff];
        acc[ct] = __builtin_amdgcn_mfma_f32_16x16x32_bf16(av, bvv, acc[ct], 0, 0, 0);
      }
    }
    if (t < 128) { // ksum[i] = row-sum of Kb^T row i (swizzle-aware octet reads)
      float s = 0.f;
      int sw = ((t >> 3) & 7) << 3;
#pragma unroll 4
      for (int g = 0; g < 128; g += 8) {
        s16x8 v = *(const s16x8*)&sm.KT[t][g ^ sw];
#pragma unroll
        for (int e = 0; e < 8; e++) s += b2f((u16)v[e]);
      }
      ksum[(size_t)(bnh * 16 + c) * 128 + t] = s;
    }
    __syncthreads();
    { // C-layout -> KT (as S^T[j][i], plain layout)
      int lbase = (w << 4) + (quad << 2);
#pragma unroll
      for (int ct = 0; ct < 8; ct++) {
        int i = (ct << 4) + nl;
#pragma unroll
        for (int r = 0; r < 4; r++) sm.KT[lbase + r][i] = f2b(acc[ct][r]);
      }
    }
    __syncthreads();
    size_t sbase = ((size_t)(bnh * 16 + c)) << 14;
    for (int idx = t; idx < 2048; idx += 512) {
      int jr = idx >> 4, g = (idx & 15) << 3;
      *(s16x8*)(sct + sbase + ((size_t)jr << 7) + g) = *(const s16x8*)&sm.KT[jr][g];
    }
  }
}

// ---------------- P1b: in-place exclusive prefix over chunks, vectorized
__global__ __launch_bounds__(256) void p1b(u16* __restrict__ sct, float* __restrict__ ksum) {
  int bid = blockIdx.x, t = threadIdx.x;
  if (bid < 768) {
    int tid = bid * 256 + t;          // 0..196607
    int bnh = tid >> 11, rem = tid & 2047;
    size_t base = ((size_t)bnh << 18) + ((size_t)rem << 3);
    float acc[8] = {0.f, 0.f, 0.f, 0.f, 0.f, 0.f, 0.f, 0.f};
    for (int c = 0; c < 16; c++) {
      size_t a = base + ((size_t)c << 14);
      s16x8 v = *(const s16x8*)(sct + a);
      s16x8 o;
#pragma unroll
      for (int e = 0; e < 8; e++) { o[e] = (short)f2b(acc[e]); acc[e] += b2f((u16)v[e]); }
      *(s16x8*)(sct + a) = o;
    }
  } else {
    int m2 = (bid - 768) * 256 + t;   // 0..12287
    int i = m2 & 127, bnh = m2 >> 7;
    size_t base = (size_t)bnh * 2048 + i;
    float acc = 0.f;
    for (int c = 0; c < 16; c++) {
      size_t a = base + (size_t)c * 128;
      float v = ksum[a];
      ksum[a] = acc;
      acc += v;
    }
  }
}

// ---------------- P3 v3 (fused k_qfeat): proj MFMA + Q features in-block, then 3-branch
// inter MFMA, mask, intra PV, output. Qb/zint never touch global memory.
__global__ __launch_bounds__(512, 4) void p3(const float* __restrict__ q2g, const float* __restrict__ qg,
                                             const u16* __restrict__ wtg, const float* __restrict__ osum,
                                             const float* __restrict__ kspre,
                                             const u16* __restrict__ kb3, const u16* __restrict__ vtg,
                                             const u16* __restrict__ sct, float* __restrict__ outg) {
  __shared__ union {
    struct { alignas(16) u16 T0[128][128]; alignas(16) u16 T1[128][128]; } s;
    alignas(16) float O[128][132];
  } sm;
  __shared__ float zl[128];
  __shared__ float osb[128];
  int bid = blockIdx.x, t = threadIdx.x;
  int c = bid & 15, h = (bid >> 4) & 7, n = bid >> 7;
  int l0c = c << 7, nh = (n << 3) + h;
  int lane = t & 63, quad = lane >> 4, nl = lane & 15, w = t >> 6;
  const float invL = 1.0f / 2048.0f;
  if (t < 128) osb[t] = osum[h * 128 + t];
  // ---- stage omega^T[h] -> T1 (octet-swizzled)
  for (int idx = t; idx < 2048; idx += 512) {
    int j = idx >> 4;
    int co = (((idx & 15) ^ (j & 7)) << 3);
    *(s16x8*)&sm.s.T1[j][co] = *(const s16x8*)(wtg + ((size_t)(h * 128 + j)) * 128 + ((idx & 15) << 3));
  }
  __syncthreads();
  // ---- proj = q2 @ omega (accP temp)
  f32x4 z4 = {0.f, 0.f, 0.f, 0.f};
  f32x4 accP[8], accO[8];
#pragma unroll
  for (int i = 0; i < 8; i++) { accP[i] = z4; accO[i] = z4; }
  int arow = l0c + (w << 4) + nl;
  for (int ks = 0; ks < 4; ks++) {
    int k0 = (ks << 5) + (quad << 3);
    const float* ap = q2g + (((size_t)(n * Ln + arow) * 8 + h) << 7) + k0;
    s16x8 avq = pack8(*(const f32x4*)ap, *(const f32x4*)(ap + 4));
#pragma unroll
    for (int ct = 0; ct < 8; ct++) {
      int r = (ct << 4) + nl;
      s16x8 bv = *(const s16x8*)&sm.s.T1[r][k0 ^ ((r & 7) << 3)];
      accP[ct] = __builtin_amdgcn_mfma_f32_16x16x32_bf16(avq, bv, accP[ct], 0, 0, 0);
    }
  }
  __syncthreads();
  // ---- sin^2(proj) -> T0 (bf16, row-swizzled octets)
  int lbase = (w << 4) + (quad << 2);
#pragma unroll
  for (int ct = 0; ct < 8; ct++) {
    int j = (ct << 4) + nl;
#pragma unroll
    for (int r = 0; r < 4; r++) {
      int row = lbase + r;
      float sp = __sinf(accP[ct][r]);
      sm.s.T0[row][((((j >> 3) ^ (row & 7)) << 3) | (j & 7))] = f2b(sp * sp);
    }
  }
  __syncthreads();
  // ---- readback sin^2 to regs + Z_inter pass (bit-exact k_qfeat order)
  s16x8 s2r[4];
#pragma unroll
  for (int it = 0; it < 4; it++) {
    int idx = t + (it << 9);
    int l = idx >> 4, oct = idx & 15, j0 = oct << 3, gl = l0c + l;
    s16x8 s2v = *(const s16x8*)&sm.s.T0[l][(oct ^ (l & 7)) << 3];
    s2r[it] = s2v;
    const float* qp = qg + (((size_t)(n * Ln + gl) * 8 + h) << 7) + j0;
    f32x4 qa = *(const f32x4*)qp, qbv = *(const f32x4*)(qp + 4);
    size_t kbb = ((size_t)nh * 16 + c) * 128 + j0;
    f32x4 kp0a = *(const f32x4*)(kspre + kbb),           kp0b = *(const f32x4*)(kspre + kbb + 4);
    f32x4 kp1a = *(const f32x4*)(kspre + kbb + KSB),     kp1b = *(const f32x4*)(kspre + kbb + KSB + 4);
    f32x4 kp2a = *(const f32x4*)(kspre + kbb + 2 * KSB), kp2b = *(const f32x4*)(kspre + kbb + 2 * KSB + 4);
    float z = 0.f;
    float tb = (float)gl * invL;
#pragma unroll
    for (int e = 0; e < 8; e++) {
      float s2p = b2f((u16)s2v[e]);
      float qv = (e < 4) ? qa[e] : qbv[e - 4];
      float f = qv > 0.f ? qv + 1.f : __expf(qv);
      float Qt = s2p * f;
      float tt = tb * osb[j0 + e];
      float s, cc; __sincosf(tt, &s, &cc);
      float v0 = Qt * s * s, v1 = Qt * cc * cc, v2 = -2.f * Qt * s * cc;
      float k0v = (e < 4) ? kp0a[e] : kp0b[e - 4];
      float k1v = (e < 4) ? kp1a[e] : kp1b[e - 4];
      float k2v = (e < 4) ? kp2a[e] : kp2b[e - 4];
      z += v0 * k0v + v1 * k1v + v2 * k2v;
    }
    z += __shfl_xor(z, 1); z += __shfl_xor(z, 2);
    z += __shfl_xor(z, 4); z += __shfl_xor(z, 8);
    if (nl == 0) zl[l] = z;
  }
#pragma unroll
  for (int i = 0; i < 8; i++) accP[i] = z4; // re-zero for inter accumulation
  // ---- 3-branch loop: Qb_b stage -> A-frags -> Kb/S^T stage -> double MFMA
  for (int b = 0; b < 3; b++) {
    int bnh = b * 32 + nh;
    __syncthreads(); // prev MFMA/T0-sin2 reads done before overwrites
#pragma unroll
    for (int it = 0; it < 4; it++) { // Qb_b -> T1 (recompute weights; values bit-identical)
      int idx = t + (it << 9);
      int l = idx >> 4, oct = idx & 15, j0 = oct << 3, gl = l0c + l;
      s16x8 s2v = s2r[it];
      const float* qp = qg + (((size_t)(n * Ln + gl) * 8 + h) << 7) + j0;
      f32x4 qa = *(const f32x4*)qp, qbv = *(const f32x4*)(qp + 4);
      float tb = (float)gl * invL;
      s16x8 o;
#pragma unroll
      for (int e = 0; e < 8; e++) {
        float s2p = b2f((u16)s2v[e]);
        float qv = (e < 4) ? qa[e] : qbv[e - 4];
        float f = qv > 0.f ? qv + 1.f : __expf(qv);
        float Qt = s2p * f;
        float tt = tb * osb[j0 + e];
        float s, cc; __sincosf(tt, &s, &cc);
        float vb;
        if (b == 0) vb = Qt * s * s;
        else if (b == 1) vb = Qt * cc * cc;
        else vb = -2.f * Qt * s * cc;
        o[e] = (short)f2b(vb);
      }
      *(s16x8*)&sm.s.T1[l][(oct ^ (l & 7)) << 3] = o;
    }
    __syncthreads();
    s16x8 av[4];
    {
      int rl = (w << 4) + nl;
#pragma unroll
      for (int ks = 0; ks < 4; ks++) {
        int k0 = (ks << 5) + (quad << 3);
        av[ks] = *(const s16x8*)&sm.s.T1[rl][k0 ^ ((rl & 7) << 3)];
      }
    }
    for (int idx = t; idx < 2048; idx += 512) { // T0 <- Kb chunk [s][i], swizzled octets
      int s = idx >> 4;
      int co = (((idx & 15) ^ (s & 7)) << 3);
      *(s16x8*)&sm.s.T0[s][co] = *(const s16x8*)(kb3 + (((size_t)bnh * Ln + l0c + s) << 7) + ((idx & 15) << 3));
    }
    __syncthreads(); // av reads done; T0 staged
    size_t sbase = ((size_t)(bnh * 16 + c)) << 14;
    for (int idx = t; idx < 2048; idx += 512) { // T1 <- Sprefix^T [j][i], swizzled octets
      int j = idx >> 4;
      int co = (((idx & 15) ^ (j & 7)) << 3);
      *(s16x8*)&sm.s.T1[j][co] = *(const s16x8*)(sct + sbase + ((size_t)j << 7) + ((idx & 15) << 3));
    }
    __syncthreads();
    for (int ks = 0; ks < 4; ks++) {
      int k0 = (ks << 5) + (quad << 3);
#pragma unroll
      for (int ct = 0; ct < 8; ct++) {
        int r = (ct << 4) + nl;
        int koff = k0 ^ ((r & 7) << 3);       // unswizzle
        s16x8 bv0 = *(const s16x8*)&sm.s.T0[r][koff];
        accP[ct] = __builtin_amdgcn_mfma_f32_16x16x32_bf16(av[ks], bv0, accP[ct], 0, 0, 0);
        s16x8 bv1 = *(const s16x8*)&sm.s.T1[r][koff];
        accO[ct] = __builtin_amdgcn_mfma_f32_16x16x32_bf16(av[ks], bv1, accO[ct], 0, 0, 0);
      }
    }
  }
  __syncthreads();
  // masked P -> T0 as P[l][s] (bf16, swizzled) + register row-sums; stage T1 <- V^T [j][sc]
  float zP[4] = {0.f, 0.f, 0.f, 0.f};
#pragma unroll
  for (int ct = 0; ct < 8; ct++) {
    int ss = (ct << 4) + nl;
#pragma unroll
    for (int r = 0; r < 4; r++) {
      int lr = lbase + r;
      float pv = (ss <= lr) ? accP[ct][r] : 0.f;
      zP[r] += pv;
      sm.s.T0[lr][ss ^ ((lr & 7) << 3)] = f2b(pv);
    }
  }
#pragma unroll
  for (int mteam = 1; mteam <= 8; mteam <<= 1) {
#pragma unroll
    for (int r = 0; r < 4; r++) zP[r] += __shfl_xor(zP[r], mteam);
  }
  size_t vbase = ((size_t)(nh * 16 + c)) << 14;
  for (int idx = t; idx < 2048; idx += 512) { // T1 <- V^T chunk (linear 32KB stream), swizzled
    int j = idx >> 4;
    int co = (((idx & 15) ^ (j & 7)) << 3);
    *(s16x8*)&sm.s.T1[j][co] = *(const s16x8*)(vtg + vbase + ((size_t)idx << 3));
  }
  float zf[4];
#pragma unroll
  for (int r = 0; r < 4; r++)
    zf[r] = zl[lbase + r] + zP[r] + 1e-6f;
  __syncthreads();
  // intra: A = masked P (T0 rows l, k=s), B = V^T (T1 rows j, k=s)
  for (int ks = 0; ks < 4; ks++) {
    int k0 = (ks << 5) + (quad << 3);
    int rw = (w << 4) + nl;
    s16x8 pav = *(const s16x8*)&sm.s.T0[rw][k0 ^ ((rw & 7) << 3)];
#pragma unroll
    for (int ct = 0; ct < 8; ct++) {
      int r = (ct << 4) + nl;
      s16x8 vv = *(const s16x8*)&sm.s.T1[r][k0 ^ ((r & 7) << 3)];
      accO[ct] = __builtin_amdgcn_mfma_f32_16x16x32_bf16(pav, vv, accO[ct], 0, 0, 0);
    }
  }
  __syncthreads();
  // divided result -> fp32 LDS overlay (T0/T1 dead now)
#pragma unroll
  for (int ct = 0; ct < 8; ct++) {
    int j = (ct << 4) + nl;
#pragma unroll
    for (int r = 0; r < 4; r++) sm.O[lbase + r][j] = accO[ct][r] / zf[r];
  }
  __syncthreads();
  for (int idx = t; idx < 4096; idx += 512) { // full 512B-row coalesced stores
    int l = idx >> 5, g = (idx & 31) << 2;
    *(f32x4*)(outg + (((size_t)(n * Ln + l0c + l) * 8 + h) << 7) + g) = *(const f32x4*)&sm.O[l][g];
  }
}

extern "C" void kernel_launch(void* const* d_in, const int* in_sizes, int n_in,
                              void* d_out, int out_size, void* d_ws, size_t ws_size,
                              hipStream_t stream) {
  (void)in_sizes; (void)n_in; (void)out_size; (void)ws_size;
  const float* q   = (const float*)d_in[0];
  const float* q2  = (const float*)d_in[1];
  const float* kk  = (const float*)d_in[2];
  const float* vv  = (const float*)d_in[3];
  const float* kl  = (const float*)d_in[4];
  const float* om  = (const float*)d_in[5];
  float* out = (float*)d_out;

  // workspace carve (bf16 region then fp32 region) — ~120 MB (qb3/zint eliminated)
  u16* W     = (u16*)d_ws;
  u16* kb3   = W;                 // 3*NHLD (naturals; k_kvs transposes in-block, L2-hot)
  u16* vt    = W + 3 * NHLD;      // NHLD   (chunk-blocked [nh][c][i][sc])
  u16* sct   = W + 4 * NHLD;      // 3*NHLD (chunk sums -> exclusive prefix, in place)
  u16* wt    = W + 7 * NHLD;      // 131072 (omega^T bf16)
  float* ks  = (float*)(W + 7 * NHLD + 131072); // 196608 f32 (chunk Ksum -> prefix)
  float* osm = ks + 196608;       // 1024 f32

  k_omega <<<8,    256, 0, stream>>>(om, wt, osm);
  k_kvs   <<<512,  512, 0, stream>>>(kk, vv, kl, osm, kb3, vt, sct, ks);
  p1b     <<<816,  256, 0, stream>>>(sct, ks);
  p3      <<<512,  512, 0, stream>>>(q2, q, wt, osm, ks, kb3, vt, sct, out);
}

// Round 10
// 288.542 us; speedup vs baseline: 1.0172x; 1.0172x over previous
//
#include <hip/hip_runtime.h>

// CausalLinearRelativeAttention — chunked 3-branch causal linear attention, bf16 MFMA.
// N=4, L=2048, H=8, D=Dv=128, chunk C=128, T=16 chunks, 3 branches (coeff -2 folded into Qb2).
// R8: dropped kbt3. R11: k_kvfeat+p1a fused (k_kvs). R12: full q-fusion regressed (spills).
// R14: Qt intermediate — k_qfeat stores fp32 Qt (32MB) instead of 3-branch bf16 qb3 (48MB);
//      p3 recomputes branch weights {s^2,c^2,-2sc} per-thread from (l,j) trig when building
//      A-fragments (register-only; same barrier structure as R11; bit-exact vs qb3 path).

typedef float f32x4 __attribute__((ext_vector_type(4)));
typedef short s16x8 __attribute__((ext_vector_type(8)));
typedef short s16x4 __attribute__((ext_vector_type(4)));
typedef unsigned short u16;

static constexpr int    Ln   = 2048;
static constexpr size_t NHLD = (size_t)32 * 2048 * 128; // per-branch feature elems = 8,388,608
static constexpr size_t KSB  = (size_t)32 * 16 * 128;   // kspre per-branch stride = 65536

__device__ __forceinline__ float b2f(u16 s) {
  union { unsigned u; float f; } x; x.u = ((unsigned)s) << 16; return x.f;
}
__device__ __forceinline__ u16 f2b(float f) {
  union { float f; unsigned u; } x; x.f = f;
  unsigned r = x.u + 0x7fffu + ((x.u >> 16) & 1u);
  return (u16)(r >> 16);
}
__device__ __forceinline__ s16x8 pack8(f32x4 a, f32x4 b) {
  s16x8 r;
  r[0] = (short)f2b(a[0]); r[1] = (short)f2b(a[1]); r[2] = (short)f2b(a[2]); r[3] = (short)f2b(a[3]);
  r[4] = (short)f2b(b[0]); r[5] = (short)f2b(b[1]); r[6] = (short)f2b(b[2]); r[7] = (short)f2b(b[3]);
  return r;
}

// ---------------------------------------------------------------- K0: omega^T (bf16) + column sums
__global__ __launch_bounds__(256) void k_omega(const float* __restrict__ om,
                                               u16* __restrict__ wt, float* __restrict__ osum) {
  __shared__ alignas(16) u16 T[128][136];
  int h = blockIdx.x, t = threadIdx.x;
  for (int idx = t; idx < 128 * 32; idx += 256) {
    int i = idx >> 5, cs = (idx & 31) << 2;
    f32x4 vv = *(const f32x4*)(om + ((size_t)(h * 128 + i)) * 128 + cs);
    T[i][cs + 0] = f2b(vv[0]); T[i][cs + 1] = f2b(vv[1]);
    T[i][cs + 2] = f2b(vv[2]); T[i][cs + 3] = f2b(vv[3]);
  }
  if (t < 128) { // exact fp32 column sums (coalesced per row)
    float acc = 0.f;
    for (int i = 0; i < 128; i++) acc += om[((size_t)(h * 128 + i)) * 128 + t];
    osum[h * 128 + t] = acc;
  }
  __syncthreads();
  { // transposed write: wt[h][j][i] = omega[h][i][j]
    int j = t >> 1, lh = (t & 1) << 6;
    s16x8* dst = (s16x8*)(wt + ((size_t)(h * 128 + j)) * 128 + lh);
    for (int u = 0; u < 8; u++) {
      s16x8 pv;
#pragma unroll
      for (int e = 0; e < 8; e++) pv[e] = (short)T[lh + u * 8 + e][j];
      dst[u] = pv;
    }
  }
}

// ---------------------- K1+P1a fused (k_kvs): one block per (n,h,c), 512 threads. (unchanged R11)
__global__ __launch_bounds__(512) void k_kvs(const float* __restrict__ kg, const float* __restrict__ vg,
                                             const float* __restrict__ klg, const float* __restrict__ osum,
                                             u16* __restrict__ kb3, u16* __restrict__ vt,
                                             u16* __restrict__ sct, float* __restrict__ ksum) {
  __shared__ union {
    alignas(16) u16 VT[128][128]; // V natural [s][i], swizzled granules (phase A/B)
    alignas(16) u16 KT[128][136]; // Kb^T [i][s] swizzled; then S^T staging (phase C)
  } sm;
  int bid = blockIdx.x, t = threadIdx.x;
  int c = bid & 15, h = (bid >> 4) & 7, n = bid >> 7;
  int l0 = c << 7, nh = (n << 3) + h;
  const float invL = 1.0f / 2048.0f;
  int gcol = t & 31, cs = gcol << 2;          // column quad fixed per thread
  f32x4 osv = *(const f32x4*)(osum + h * 128 + cs);
  // ---- phase A: features + kb3 direct stores + VT build
#pragma unroll
  for (int it = 0; it < 8; it++) {
    int rr = (it << 4) + (t >> 5);            // row in chunk 0..127
    int l = l0 + rr;
    size_t gb = (((size_t)(n * Ln + l) * 8 + h) << 7) + cs;
    f32x4 kv = *(const f32x4*)(kg + gb);
    f32x4 vv = *(const f32x4*)(vg + gb);
    float klv = klg[n * Ln + l];
    float tb = (float)l * invL;
    u16 r0[4], r1[4], r2[4];
#pragma unroll
    for (int e = 0; e < 4; e++) {
      float kf = (kv[e] > 0.f ? kv[e] + 1.f : __expf(kv[e])) * klv;
      float tt = tb * osv[e];
      float s, cc; __sincosf(tt, &s, &cc);
      r0[e] = f2b(kf * cc * cc);
      r1[e] = f2b(kf * s * s);
      r2[e] = f2b(kf * s * cc);
    }
    int gs = (gcol ^ (rr >> 3)) << 2;         // swizzled granule (4 u16)
    *(s16x4*)&sm.VT[rr][gs] = (s16x4){(short)f2b(vv[0]), (short)f2b(vv[1]),
                                      (short)f2b(vv[2]), (short)f2b(vv[3])};
    size_t nb = ((size_t)nh * Ln + l) * 128 + cs;
    *(s16x4*)(kb3 + nb)          = (s16x4){(short)r0[0], (short)r0[1], (short)r0[2], (short)r0[3]};
    *(s16x4*)(kb3 + NHLD + nb)   = (s16x4){(short)r1[0], (short)r1[1], (short)r1[2], (short)r1[3]};
    *(s16x4*)(kb3 + 2*NHLD + nb) = (s16x4){(short)r2[0], (short)r2[1], (short)r2[2], (short)r2[3]};
  }
  __syncthreads();
  // ---- phase B: stream V^T chunk out (contiguous 32KB, full-line writes)
  size_t bv = ((size_t)(nh * 16 + c)) << 14;
  for (int idx = t; idx < 2048; idx += 512) {
    int i = idx >> 4, o = idx & 15;
    int gp = (((i >> 2) ^ o) << 2) + (i & 3);
    s16x8 v1;
#pragma unroll
    for (int u = 0; u < 8; u++) v1[u] = (short)sm.VT[(o << 3) + u][gp];
    *(s16x8*)(vt + bv + (((size_t)i) << 7) + (o << 3)) = v1;
  }
  // ---- phase C: per-branch chunk-S^T (operands L2-hot)
  int lane = t & 63, quad = lane >> 4, nl = lane & 15, w = t >> 6;
  int arow = (w << 4) + nl;                   // j row, 8 waves x 16 = 128
  const u16* vchunk = vt + bv;
  for (int b = 0; b < 3; b++) {
    int bnh = b * 32 + nh;
    const u16* kb = kb3 + (size_t)b * NHLD + ((size_t)nh * Ln + l0) * 128;
    __syncthreads();                          // VT reads / prev sct stream done before KT overwrite
    for (int idx = t; idx < 2048; idx += 512) {
      int s = idx >> 4, io = idx & 15;        // natural row s, i-octet io
      s16x8 v = *(const s16x8*)(kb + (((size_t)s) << 7) + (io << 3)); // L2-hot (own writes)
      int cp = s ^ ((io & 7) << 3);           // swizzled phys column
#pragma unroll
      for (int j = 0; j < 8; j++) sm.KT[(io << 3) + j][cp] = (u16)(short)v[j];
    }
    __syncthreads();
    f32x4 z4 = {0.f, 0.f, 0.f, 0.f};
    f32x4 acc[8];
#pragma unroll
    for (int i = 0; i < 8; i++) acc[i] = z4;
    for (int ks = 0; ks < 4; ks++) {
      int k0 = (ks << 5) + (quad << 3);
      s16x8 av = *(const s16x8*)(vchunk + (((size_t)arow) << 7) + k0); // L2-hot
#pragma unroll
      for (int ct = 0; ct < 8; ct++) {
        int r = (ct << 4) + nl;
        int koff = k0 ^ (((r >> 3) & 7) << 3); // unswizzle octet
        s16x8 bvv = *(const s16x8*)&sm.KT[r][koff];
        acc[ct] = __builtin_amdgcn_mfma_f32_16x16x32_bf16(av, bvv, acc[ct], 0, 0, 0);
      }
    }
    if (t < 128) { // ksum[i] = row-sum of Kb^T row i (swizzle-aware octet reads)
      float s = 0.f;
      int sw = ((t >> 3) & 7) << 3;
#pragma unroll 4
      for (int g = 0; g < 128; g += 8) {
        s16x8 v = *(const s16x8*)&sm.KT[t][g ^ sw];
#pragma unroll
        for (int e = 0; e < 8; e++) s += b2f((u16)v[e]);
      }
      ksum[(size_t)(bnh * 16 + c) * 128 + t] = s;
    }
    __syncthreads();
    { // C-layout -> KT (as S^T[j][i], plain layout)
      int lbase = (w << 4) + (quad << 2);
#pragma unroll
      for (int ct = 0; ct < 8; ct++) {
        int i = (ct << 4) + nl;
#pragma unroll
        for (int r = 0; r < 4; r++) sm.KT[lbase + r][i] = f2b(acc[ct][r]);
      }
    }
    __syncthreads();
    size_t sbase = ((size_t)(bnh * 16 + c)) << 14;
    for (int idx = t; idx < 2048; idx += 512) {
      int jr = idx >> 4, g = (idx & 15) << 3;
      *(s16x8*)(sct + sbase + ((size_t)jr << 7) + g) = *(const s16x8*)&sm.KT[jr][g];
    }
  }
}

// ---------------- P1b: in-place exclusive prefix over chunks, vectorized (unchanged)
__global__ __launch_bounds__(256) void p1b(u16* __restrict__ sct, float* __restrict__ ksum) {
  int bid = blockIdx.x, t = threadIdx.x;
  if (bid < 768) {
    int tid = bid * 256 + t;          // 0..196607
    int bnh = tid >> 11, rem = tid & 2047;
    size_t base = ((size_t)bnh << 18) + ((size_t)rem << 3);
    float acc[8] = {0.f, 0.f, 0.f, 0.f, 0.f, 0.f, 0.f, 0.f};
    for (int c = 0; c < 16; c++) {
      size_t a = base + ((size_t)c << 14);
      s16x8 v = *(const s16x8*)(sct + a);
      s16x8 o;
#pragma unroll
      for (int e = 0; e < 8; e++) { o[e] = (short)f2b(acc[e]); acc[e] += b2f((u16)v[e]); }
      *(s16x8*)(sct + a) = o;
    }
  } else {
    int m2 = (bid - 768) * 256 + t;   // 0..12287
    int i = m2 & 127, bnh = m2 >> 7;
    size_t base = (size_t)bnh * 2048 + i;
    float acc = 0.f;
    for (int c = 0; c < 16; c++) {
      size_t a = base + (size_t)c * 128;
      float v = ksum[a];
      ksum[a] = acc;
      acc += v;
    }
  }
}

// ---------------- K2: proj = q2 @ omega (MFMA), Qt (fp32) + Z_inter fused
// Qt[nh][l][j] = sin^2(proj) * elu1(q); zint[nh][l] = sum_b <Qb[l], ksum_prefix_b[c(l)]>
__global__ __launch_bounds__(256, 2) void k_qfeat(const float* __restrict__ q2g, const float* __restrict__ qg,
                                                  const u16* __restrict__ wt, const float* __restrict__ osum,
                                                  const float* __restrict__ kspre,
                                                  float* __restrict__ qtg, float* __restrict__ zintg) {
  __shared__ alignas(16) u16 B[128][136]; // omega^T[h]; later reused rows 0..63 for sin^2(proj)
  __shared__ float osb[128];
  int bid = blockIdx.x, t = threadIdx.x;
  int m = bid & 31, h = (bid >> 5) & 7, n = bid >> 8;
  int l0 = m << 6, c = m >> 1, nh = (n << 3) + h;
  if (t < 128) osb[t] = osum[h * 128 + t];
  for (int idx = t; idx < 2048; idx += 256) {
    int j = idx >> 4, cs = (idx & 15) << 3;
    *(s16x8*)&B[j][cs] = *(const s16x8*)(wt + ((size_t)(h * 128 + j)) * 128 + cs);
  }
  __syncthreads();
  int lane = t & 63, quad = lane >> 4, nl = lane & 15, w = t >> 6;
  f32x4 z4 = {0.f, 0.f, 0.f, 0.f};
  f32x4 acc[8];
#pragma unroll
  for (int i = 0; i < 8; i++) acc[i] = z4;
  int arow = l0 + (w << 4) + nl;
  for (int ks = 0; ks < 4; ks++) {
    int k0 = (ks << 5) + (quad << 3);
    const float* ap = q2g + (((size_t)(n * Ln + arow) * 8 + h) << 7) + k0;
    s16x8 av = pack8(*(const f32x4*)ap, *(const f32x4*)(ap + 4));
#pragma unroll
    for (int ct = 0; ct < 8; ct++) {
      s16x8 bv = *(const s16x8*)&B[(ct << 4) + nl][k0];
      acc[ct] = __builtin_amdgcn_mfma_f32_16x16x32_bf16(av, bv, acc[ct], 0, 0, 0);
    }
  }
  __syncthreads();
  { // sin^2(proj) -> B rows 0..63
    int lbase = (w << 4) + (quad << 2);
#pragma unroll
    for (int ct = 0; ct < 8; ct++) {
      int j = (ct << 4) + nl;
#pragma unroll
      for (int r = 0; r < 4; r++) {
        float sp = __sinf(acc[ct][r]);
        B[lbase + r][j] = f2b(sp * sp);
      }
    }
  }
  __syncthreads();
  const float invL = 1.0f / 2048.0f;
  for (int idx = t; idx < 1024; idx += 256) {
    int l = idx >> 4, j0 = (idx & 15) << 3, gl = l0 + l;
    s16x8 s2v = *(const s16x8*)&B[l][j0];
    const float* qp = qg + (((size_t)(n * Ln + gl) * 8 + h) << 7) + j0;
    f32x4 qa = *(const f32x4*)qp, qbv = *(const f32x4*)(qp + 4);
    size_t kbb = ((size_t)nh * 16 + c) * 128 + j0;
    f32x4 kp0a = *(const f32x4*)(kspre + kbb),           kp0b = *(const f32x4*)(kspre + kbb + 4);
    f32x4 kp1a = *(const f32x4*)(kspre + kbb + KSB),     kp1b = *(const f32x4*)(kspre + kbb + KSB + 4);
    f32x4 kp2a = *(const f32x4*)(kspre + kbb + 2 * KSB), kp2b = *(const f32x4*)(kspre + kbb + 2 * KSB + 4);
    f32x4 qt0, qt1;
    float z = 0.f;
    float tb = (float)gl * invL;
#pragma unroll
    for (int e = 0; e < 8; e++) {
      float s2p = b2f((u16)s2v[e]);
      float qv = (e < 4) ? qa[e] : qbv[e - 4];
      float f = qv > 0.f ? qv + 1.f : __expf(qv);
      float Qt = s2p * f;
      float tt = tb * osb[j0 + e];
      float s, cc; __sincosf(tt, &s, &cc);
      float v0 = Qt * s * s, v1 = Qt * cc * cc, v2 = -2.f * Qt * s * cc;
      float k0v = (e < 4) ? kp0a[e] : kp0b[e - 4];
      float k1v = (e < 4) ? kp1a[e] : kp1b[e - 4];
      float k2v = (e < 4) ? kp2a[e] : kp2b[e - 4];
      z += v0 * k0v + v1 * k1v + v2 * k2v;
      if (e < 4) qt0[e] = Qt; else qt1[e - 4] = Qt;
    }
    size_t base = ((size_t)nh * Ln + gl) * 128 + j0;
    *(f32x4*)(qtg + base)     = qt0;
    *(f32x4*)(qtg + base + 4) = qt1;
    z += __shfl_xor(z, 1); z += __shfl_xor(z, 2);
    z += __shfl_xor(z, 4); z += __shfl_xor(z, 8);
    if (nl == 0) zintg[(size_t)nh * Ln + gl] = z;
  }
}

// ---------------- P3: R11 structure; A-fragments computed per-thread from fp32 Qt + trig
// (bit-exact vs the old qb3 loads: same fp32 exprs, same f2b).
__global__ __launch_bounds__(512, 4) void p3(const float* __restrict__ qtg, const float* __restrict__ osum,
                                             const u16* __restrict__ kb3, const u16* __restrict__ vtg,
                                             const u16* __restrict__ sct, const float* __restrict__ zintg,
                                             float* __restrict__ outg) {
  __shared__ union {
    struct { alignas(16) u16 T0[128][128]; alignas(16) u16 T1[128][128]; } s;
    alignas(16) float O[128][132];
  } sm;
  __shared__ float osb[128];
  int bid = blockIdx.x, t = threadIdx.x;
  int c = bid & 15, h = (bid >> 4) & 7, n = bid >> 7;
  int l0c = c << 7, nh = (n << 3) + h;
  int lane = t & 63, quad = lane >> 4, nl = lane & 15, w = t >> 6;
  const float invL = 1.0f / 2048.0f;
  if (t < 128) osb[t] = osum[h * 128 + t];
  f32x4 z4 = {0.f, 0.f, 0.f, 0.f};
  f32x4 accP[8], accO[8];
#pragma unroll
  for (int i = 0; i < 8; i++) { accP[i] = z4; accO[i] = z4; }
  int arow = l0c + (w << 4) + nl;
  const float* qrow = qtg + (((size_t)nh * Ln + arow) << 7);
  float tbq = (float)arow * invL;
  for (int b = 0; b < 3; b++) {
    int bnh = b * 32 + nh;
    __syncthreads(); // also covers osb readiness on first iteration
    for (int idx = t; idx < 2048; idx += 512) { // T0 <- Kb chunk [s][i], swizzled octets
      int s = idx >> 4;
      int co = (((idx & 15) ^ (s & 7)) << 3);
      *(s16x8*)&sm.s.T0[s][co] = *(const s16x8*)(kb3 + (((size_t)bnh * Ln + l0c + s) << 7) + ((idx & 15) << 3));
    }
    size_t sbase = ((size_t)(bnh * 16 + c)) << 14;
    for (int idx = t; idx < 2048; idx += 512) { // T1 <- Sprefix^T [j][i], swizzled octets
      int j = idx >> 4;
      int co = (((idx & 15) ^ (j & 7)) << 3);
      *(s16x8*)&sm.s.T1[j][co] = *(const s16x8*)(sct + sbase + ((size_t)j << 7) + ((idx & 15) << 3));
    }
    s16x8 av[4]; // A-fragments from Qt + branch trig weights (registers only; pre-barrier)
#pragma unroll
    for (int ks = 0; ks < 4; ks++) {
      int k0 = (ks << 5) + (quad << 3);
      f32x4 qA = *(const f32x4*)(qrow + k0);
      f32x4 qB = *(const f32x4*)(qrow + k0 + 4);
#pragma unroll
      for (int e = 0; e < 8; e++) {
        float Qt = (e < 4) ? qA[e] : qB[e - 4];
        float tt = tbq * osb[k0 + e];
        float s, cc; __sincosf(tt, &s, &cc);
        float vb;
        if (b == 0) vb = Qt * s * s;
        else if (b == 1) vb = Qt * cc * cc;
        else vb = -2.f * Qt * s * cc;
        av[ks][e] = (short)f2b(vb);
      }
    }
    __syncthreads();
    for (int ks = 0; ks < 4; ks++) {
      int k0 = (ks << 5) + (quad << 3);
#pragma unroll
      for (int ct = 0; ct < 8; ct++) {
        int r = (ct << 4) + nl;
        int koff = k0 ^ ((r & 7) << 3);       // unswizzle
        s16x8 bv0 = *(const s16x8*)&sm.s.T0[r][koff];
        accP[ct] = __builtin_amdgcn_mfma_f32_16x16x32_bf16(av[ks], bv0, accP[ct], 0, 0, 0);
        s16x8 bv1 = *(const s16x8*)&sm.s.T1[r][koff];
        accO[ct] = __builtin_amdgcn_mfma_f32_16x16x32_bf16(av[ks], bv1, accO[ct], 0, 0, 0);
      }
    }
  }
  __syncthreads();
  // masked P -> T0 as P[l][s] (bf16, swizzled) + register row-sums; stage T1 <- V^T [j][sc]
  float zP[4] = {0.f, 0.f, 0.f, 0.f};
  int lbase = (w << 4) + (quad << 2);
#pragma unroll
  for (int ct = 0; ct < 8; ct++) {
    int ss = (ct << 4) + nl;
#pragma unroll
    for (int r = 0; r < 4; r++) {
      int lr = lbase + r;
      float pv = (ss <= lr) ? accP[ct][r] : 0.f;
      zP[r] += pv;
      sm.s.T0[lr][ss ^ ((lr & 7) << 3)] = f2b(pv);
    }
  }
#pragma unroll
  for (int mteam = 1; mteam <= 8; mteam <<= 1) {
#pragma unroll
    for (int r = 0; r < 4; r++) zP[r] += __shfl_xor(zP[r], mteam);
  }
  size_t vbase = ((size_t)(nh * 16 + c)) << 14;
  for (int idx = t; idx < 2048; idx += 512) { // T1 <- V^T chunk (linear 32KB stream), swizzled
    int j = idx >> 4;
    int co = (((idx & 15) ^ (j & 7)) << 3);
    *(s16x8*)&sm.s.T1[j][co] = *(const s16x8*)(vtg + vbase + ((size_t)idx << 3));
  }
  float zf[4];
#pragma unroll
  for (int r = 0; r < 4; r++)
    zf[r] = zintg[(size_t)nh * Ln + l0c + lbase + r] + zP[r] + 1e-6f;
  __syncthreads();
  // intra: A = masked P (T0 rows l, k=s), B = V^T (T1 rows j, k=s)
  for (int ks = 0; ks < 4; ks++) {
    int k0 = (ks << 5) + (quad << 3);
    int rw = (w << 4) + nl;
    s16x8 pav = *(const s16x8*)&sm.s.T0[rw][k0 ^ ((rw & 7) << 3)];
#pragma unroll
    for (int ct = 0; ct < 8; ct++) {
      int r = (ct << 4) + nl;
      s16x8 vv = *(const s16x8*)&sm.s.T1[r][k0 ^ ((r & 7) << 3)];
      accO[ct] = __builtin_amdgcn_mfma_f32_16x16x32_bf16(pav, vv, accO[ct], 0, 0, 0);
    }
  }
  __syncthreads();
  // divided result -> fp32 LDS overlay (T0/T1 dead now)
#pragma unroll
  for (int ct = 0; ct < 8; ct++) {
    int j = (ct << 4) + nl;
#pragma unroll
    for (int r = 0; r < 4; r++) sm.O[lbase + r][j] = accO[ct][r] / zf[r];
  }
  __syncthreads();
  for (int idx = t; idx < 4096; idx += 512) { // full 512B-row coalesced stores
    int l = idx >> 5, g = (idx & 31) << 2;
    *(f32x4*)(outg + (((size_t)(n * Ln + l0c + l) * 8 + h) << 7) + g) = *(const f32x4*)&sm.O[l][g];
  }
}

extern "C" void kernel_launch(void* const* d_in, const int* in_sizes, int n_in,
                              void* d_out, int out_size, void* d_ws, size_t ws_size,
                              hipStream_t stream) {
  (void)in_sizes; (void)n_in; (void)out_size; (void)ws_size;
  const float* q   = (const float*)d_in[0];
  const float* q2  = (const float*)d_in[1];
  const float* kk  = (const float*)d_in[2];
  const float* vv  = (const float*)d_in[3];
  const float* kl  = (const float*)d_in[4];
  const float* om  = (const float*)d_in[5];
  float* out = (float*)d_out;

  // workspace carve (bf16 region then fp32 region) — ~151 MB (qb3 48MB -> qt 32MB)
  u16* W     = (u16*)d_ws;
  u16* kb3   = W;                 // 3*NHLD (naturals; k_kvs transposes in-block, L2-hot)
  u16* vt    = W + 3 * NHLD;      // NHLD   (chunk-blocked [nh][c][i][sc])
  u16* sct   = W + 4 * NHLD;      // 3*NHLD (chunk sums -> exclusive prefix, in place)
  u16* wt    = W + 7 * NHLD;      // 131072 (omega^T bf16)
  float* qt  = (float*)(W + 7 * NHLD + 131072); // NHLD f32 (Qt field)
  float* ks  = qt + NHLD;         // 196608 f32 (chunk Ksum -> prefix)
  float* osm = ks + 196608;       // 1024 f32
  float* zin = osm + 1024;        // 65536 f32 (Z_inter)

  k_omega <<<8,    256, 0, stream>>>(om, wt, osm);
  k_kvs   <<<512,  512, 0, stream>>>(kk, vv, kl, osm, kb3, vt, sct, ks);
  p1b     <<<816,  256, 0, stream>>>(sct, ks);
  k_qfeat <<<1024, 256, 0, stream>>>(q2, q, wt, osm, ks, qt, zin);
  p3      <<<512,  512, 0, stream>>>(qt, osm, kb3, vt, sct, zin, out);
}

// Round 11
// 266.554 us; speedup vs baseline: 1.1011x; 1.0825x over previous
//
#include <hip/hip_runtime.h>

// CausalLinearRelativeAttention — chunked 3-branch causal linear attention, bf16 MFMA.
// N=4, L=2048, H=8, D=Dv=128, chunk C=128, T=16 chunks, 3 branches (coeff -2 folded into Qb2).
// R8: dropped kbt3. R11: k_kvfeat+p1a fused (k_kvs) = best verified 269.2us.
// R12/R14: qb3-elimination attempts both measured worse -> abandoned; k_qfeat/p3 = R11 forms.
// R15: dispatch-level overlap — p1b split into p1k (ksum prefix, tiny; k_qfeat's only dep)
//      and the 96MB sct-prefix pass, which is MERGED into k_qfeat's dispatch as a disjoint
//      block range (blocks 1024..1791). The sct stream runs concurrently with k_qfeat,
//      absorbing idle BW (each kernel alone sits at ~2.8 of 6.6 TB/s). Zero arithmetic change.

typedef float f32x4 __attribute__((ext_vector_type(4)));
typedef short s16x8 __attribute__((ext_vector_type(8)));
typedef short s16x4 __attribute__((ext_vector_type(4)));
typedef unsigned short u16;

static constexpr int    Ln   = 2048;
static constexpr size_t NHLD = (size_t)32 * 2048 * 128; // per-branch feature elems = 8,388,608
static constexpr size_t KSB  = (size_t)32 * 16 * 128;   // kspre per-branch stride = 65536

__device__ __forceinline__ float b2f(u16 s) {
  union { unsigned u; float f; } x; x.u = ((unsigned)s) << 16; return x.f;
}
__device__ __forceinline__ u16 f2b(float f) {
  union { float f; unsigned u; } x; x.f = f;
  unsigned r = x.u + 0x7fffu + ((x.u >> 16) & 1u);
  return (u16)(r >> 16);
}
__device__ __forceinline__ s16x8 pack8(f32x4 a, f32x4 b) {
  s16x8 r;
  r[0] = (short)f2b(a[0]); r[1] = (short)f2b(a[1]); r[2] = (short)f2b(a[2]); r[3] = (short)f2b(a[3]);
  r[4] = (short)f2b(b[0]); r[5] = (short)f2b(b[1]); r[6] = (short)f2b(b[2]); r[7] = (short)f2b(b[3]);
  return r;
}

// ---------------------------------------------------------------- K0: omega^T (bf16) + column sums
__global__ __launch_bounds__(256) void k_omega(const float* __restrict__ om,
                                               u16* __restrict__ wt, float* __restrict__ osum) {
  __shared__ alignas(16) u16 T[128][136];
  int h = blockIdx.x, t = threadIdx.x;
  for (int idx = t; idx < 128 * 32; idx += 256) {
    int i = idx >> 5, cs = (idx & 31) << 2;
    f32x4 vv = *(const f32x4*)(om + ((size_t)(h * 128 + i)) * 128 + cs);
    T[i][cs + 0] = f2b(vv[0]); T[i][cs + 1] = f2b(vv[1]);
    T[i][cs + 2] = f2b(vv[2]); T[i][cs + 3] = f2b(vv[3]);
  }
  if (t < 128) { // exact fp32 column sums (coalesced per row)
    float acc = 0.f;
    for (int i = 0; i < 128; i++) acc += om[((size_t)(h * 128 + i)) * 128 + t];
    osum[h * 128 + t] = acc;
  }
  __syncthreads();
  { // transposed write: wt[h][j][i] = omega[h][i][j]
    int j = t >> 1, lh = (t & 1) << 6;
    s16x8* dst = (s16x8*)(wt + ((size_t)(h * 128 + j)) * 128 + lh);
    for (int u = 0; u < 8; u++) {
      s16x8 pv;
#pragma unroll
      for (int e = 0; e < 8; e++) pv[e] = (short)T[lh + u * 8 + e][j];
      dst[u] = pv;
    }
  }
}

// ---------------------- K1+P1a fused (k_kvs): one block per (n,h,c), 512 threads. (R11 verbatim)
__global__ __launch_bounds__(512) void k_kvs(const float* __restrict__ kg, const float* __restrict__ vg,
                                             const float* __restrict__ klg, const float* __restrict__ osum,
                                             u16* __restrict__ kb3, u16* __restrict__ vt,
                                             u16* __restrict__ sct, float* __restrict__ ksum) {
  __shared__ union {
    alignas(16) u16 VT[128][128]; // V natural [s][i], swizzled granules (phase A/B)
    alignas(16) u16 KT[128][136]; // Kb^T [i][s] swizzled; then S^T staging (phase C)
  } sm;
  int bid = blockIdx.x, t = threadIdx.x;
  int c = bid & 15, h = (bid >> 4) & 7, n = bid >> 7;
  int l0 = c << 7, nh = (n << 3) + h;
  const float invL = 1.0f / 2048.0f;
  int gcol = t & 31, cs = gcol << 2;          // column quad fixed per thread
  f32x4 osv = *(const f32x4*)(osum + h * 128 + cs);
  // ---- phase A: features + kb3 direct stores + VT build
#pragma unroll
  for (int it = 0; it < 8; it++) {
    int rr = (it << 4) + (t >> 5);            // row in chunk 0..127
    int l = l0 + rr;
    size_t gb = (((size_t)(n * Ln + l) * 8 + h) << 7) + cs;
    f32x4 kv = *(const f32x4*)(kg + gb);
    f32x4 vv = *(const f32x4*)(vg + gb);
    float klv = klg[n * Ln + l];
    float tb = (float)l * invL;
    u16 r0[4], r1[4], r2[4];
#pragma unroll
    for (int e = 0; e < 4; e++) {
      float kf = (kv[e] > 0.f ? kv[e] + 1.f : __expf(kv[e])) * klv;
      float tt = tb * osv[e];
      float s, cc; __sincosf(tt, &s, &cc);
      r0[e] = f2b(kf * cc * cc);
      r1[e] = f2b(kf * s * s);
      r2[e] = f2b(kf * s * cc);
    }
    int gs = (gcol ^ (rr >> 3)) << 2;         // swizzled granule (4 u16)
    *(s16x4*)&sm.VT[rr][gs] = (s16x4){(short)f2b(vv[0]), (short)f2b(vv[1]),
                                      (short)f2b(vv[2]), (short)f2b(vv[3])};
    size_t nb = ((size_t)nh * Ln + l) * 128 + cs;
    *(s16x4*)(kb3 + nb)          = (s16x4){(short)r0[0], (short)r0[1], (short)r0[2], (short)r0[3]};
    *(s16x4*)(kb3 + NHLD + nb)   = (s16x4){(short)r1[0], (short)r1[1], (short)r1[2], (short)r1[3]};
    *(s16x4*)(kb3 + 2*NHLD + nb) = (s16x4){(short)r2[0], (short)r2[1], (short)r2[2], (short)r2[3]};
  }
  __syncthreads();
  // ---- phase B: stream V^T chunk out (contiguous 32KB, full-line writes)
  size_t bv = ((size_t)(nh * 16 + c)) << 14;
  for (int idx = t; idx < 2048; idx += 512) {
    int i = idx >> 4, o = idx & 15;
    int gp = (((i >> 2) ^ o) << 2) + (i & 3);
    s16x8 v1;
#pragma unroll
    for (int u = 0; u < 8; u++) v1[u] = (short)sm.VT[(o << 3) + u][gp];
    *(s16x8*)(vt + bv + (((size_t)i) << 7) + (o << 3)) = v1;
  }
  // ---- phase C: per-branch chunk-S^T (operands L2-hot)
  int lane = t & 63, quad = lane >> 4, nl = lane & 15, w = t >> 6;
  int arow = (w << 4) + nl;                   // j row, 8 waves x 16 = 128
  const u16* vchunk = vt + bv;
  for (int b = 0; b < 3; b++) {
    int bnh = b * 32 + nh;
    const u16* kb = kb3 + (size_t)b * NHLD + ((size_t)nh * Ln + l0) * 128;
    __syncthreads();                          // VT reads / prev sct stream done before KT overwrite
    for (int idx = t; idx < 2048; idx += 512) {
      int s = idx >> 4, io = idx & 15;        // natural row s, i-octet io
      s16x8 v = *(const s16x8*)(kb + (((size_t)s) << 7) + (io << 3)); // L2-hot (own writes)
      int cp = s ^ ((io & 7) << 3);           // swizzled phys column
#pragma unroll
      for (int j = 0; j < 8; j++) sm.KT[(io << 3) + j][cp] = (u16)(short)v[j];
    }
    __syncthreads();
    f32x4 z4 = {0.f, 0.f, 0.f, 0.f};
    f32x4 acc[8];
#pragma unroll
    for (int i = 0; i < 8; i++) acc[i] = z4;
    for (int ks = 0; ks < 4; ks++) {
      int k0 = (ks << 5) + (quad << 3);
      s16x8 av = *(const s16x8*)(vchunk + (((size_t)arow) << 7) + k0); // L2-hot
#pragma unroll
      for (int ct = 0; ct < 8; ct++) {
        int r = (ct << 4) + nl;
        int koff = k0 ^ (((r >> 3) & 7) << 3); // unswizzle octet
        s16x8 bvv = *(const s16x8*)&sm.KT[r][koff];
        acc[ct] = __builtin_amdgcn_mfma_f32_16x16x32_bf16(av, bvv, acc[ct], 0, 0, 0);
      }
    }
    if (t < 128) { // ksum[i] = row-sum of Kb^T row i (swizzle-aware octet reads)
      float s = 0.f;
      int sw = ((t >> 3) & 7) << 3;
#pragma unroll 4
      for (int g = 0; g < 128; g += 8) {
        s16x8 v = *(const s16x8*)&sm.KT[t][g ^ sw];
#pragma unroll
        for (int e = 0; e < 8; e++) s += b2f((u16)v[e]);
      }
      ksum[(size_t)(bnh * 16 + c) * 128 + t] = s;
    }
    __syncthreads();
    { // C-layout -> KT (as S^T[j][i], plain layout)
      int lbase = (w << 4) + (quad << 2);
#pragma unroll
      for (int ct = 0; ct < 8; ct++) {
        int i = (ct << 4) + nl;
#pragma unroll
        for (int r = 0; r < 4; r++) sm.KT[lbase + r][i] = f2b(acc[ct][r]);
      }
    }
    __syncthreads();
    size_t sbase = ((size_t)(bnh * 16 + c)) << 14;
    for (int idx = t; idx < 2048; idx += 512) {
      int jr = idx >> 4, g = (idx & 15) << 3;
      *(s16x8*)(sct + sbase + ((size_t)jr << 7) + g) = *(const s16x8*)&sm.KT[jr][g];
    }
  }
}

// ---------------- P1k: ksum exclusive prefix over chunks (k_qfeat's only p1b dependency)
__global__ __launch_bounds__(256) void p1k(float* __restrict__ ksum) {
  int m2 = blockIdx.x * 256 + threadIdx.x;  // 0..12287
  int i = m2 & 127, bnh = m2 >> 7;
  size_t base = (size_t)bnh * 2048 + i;
  float acc = 0.f;
  for (int c = 0; c < 16; c++) {
    size_t a = base + (size_t)c * 128;
    float v = ksum[a];
    ksum[a] = acc;
    acc += v;
  }
}

// ---------------- KQM: merged k_qfeat (blocks 0..1023) + sct exclusive prefix (blocks 1024..1791).
// The two workloads are independent; running them in one dispatch overlaps the 96MB sct
// stream with k_qfeat's compute, absorbing idle BW. Both bodies are R11-verbatim.
__global__ __launch_bounds__(256, 2) void kqm(const float* __restrict__ q2g, const float* __restrict__ qg,
                                              const u16* __restrict__ wt, const float* __restrict__ osum,
                                              const float* __restrict__ kspre,
                                              u16* __restrict__ qb3, float* __restrict__ zintg,
                                              u16* __restrict__ sct) {
  __shared__ alignas(16) u16 B[128][136]; // omega^T[h]; later reused rows 0..63 for sin^2(proj)
  __shared__ float osb[128];
  int bid = blockIdx.x, t = threadIdx.x;
  if (bid >= 1024) { // ---- sct exclusive prefix over chunks (p1b body, verbatim)
    int tid = (bid - 1024) * 256 + t;  // 0..196607
    int bnh = tid >> 11, rem = tid & 2047;
    size_t base = ((size_t)bnh << 18) + ((size_t)rem << 3);
    float acc[8] = {0.f, 0.f, 0.f, 0.f, 0.f, 0.f, 0.f, 0.f};
    for (int c = 0; c < 16; c++) {
      size_t a = base + ((size_t)c << 14);
      s16x8 v = *(const s16x8*)(sct + a);
      s16x8 o;
#pragma unroll
      for (int e = 0; e < 8; e++) { o[e] = (short)f2b(acc[e]); acc[e] += b2f((u16)v[e]); }
      *(s16x8*)(sct + a) = o;
    }
    return;
  }
  // ---- k_qfeat body (R11 verbatim)
  int m = bid & 31, h = (bid >> 5) & 7, n = bid >> 8;
  int l0 = m << 6, c = m >> 1, nh = (n << 3) + h;
  if (t < 128) osb[t] = osum[h * 128 + t];
  for (int idx = t; idx < 2048; idx += 256) {
    int j = idx >> 4, cs = (idx & 15) << 3;
    *(s16x8*)&B[j][cs] = *(const s16x8*)(wt + ((size_t)(h * 128 + j)) * 128 + cs);
  }
  __syncthreads();
  int lane = t & 63, quad = lane >> 4, nl = lane & 15, w = t >> 6;
  f32x4 z4 = {0.f, 0.f, 0.f, 0.f};
  f32x4 acc[8];
#pragma unroll
  for (int i = 0; i < 8; i++) acc[i] = z4;
  int arow = l0 + (w << 4) + nl;
  for (int ks = 0; ks < 4; ks++) {
    int k0 = (ks << 5) + (quad << 3);
    const float* ap = q2g + (((size_t)(n * Ln + arow) * 8 + h) << 7) + k0;
    s16x8 av = pack8(*(const f32x4*)ap, *(const f32x4*)(ap + 4));
#pragma unroll
    for (int ct = 0; ct < 8; ct++) {
      s16x8 bv = *(const s16x8*)&B[(ct << 4) + nl][k0];
      acc[ct] = __builtin_amdgcn_mfma_f32_16x16x32_bf16(av, bv, acc[ct], 0, 0, 0);
    }
  }
  __syncthreads();
  { // sin^2(proj) -> B rows 0..63
    int lbase = (w << 4) + (quad << 2);
#pragma unroll
    for (int ct = 0; ct < 8; ct++) {
      int j = (ct << 4) + nl;
#pragma unroll
      for (int r = 0; r < 4; r++) {
        float sp = __sinf(acc[ct][r]);
        B[lbase + r][j] = f2b(sp * sp);
      }
    }
  }
  __syncthreads();
  const float invL = 1.0f / 2048.0f;
  for (int idx = t; idx < 1024; idx += 256) {
    int l = idx >> 4, j0 = (idx & 15) << 3, gl = l0 + l;
    s16x8 s2v = *(const s16x8*)&B[l][j0];
    const float* qp = qg + (((size_t)(n * Ln + gl) * 8 + h) << 7) + j0;
    f32x4 qa = *(const f32x4*)qp, qbv = *(const f32x4*)(qp + 4);
    size_t kbb = ((size_t)nh * 16 + c) * 128 + j0;
    f32x4 kp0a = *(const f32x4*)(kspre + kbb),           kp0b = *(const f32x4*)(kspre + kbb + 4);
    f32x4 kp1a = *(const f32x4*)(kspre + kbb + KSB),     kp1b = *(const f32x4*)(kspre + kbb + KSB + 4);
    f32x4 kp2a = *(const f32x4*)(kspre + kbb + 2 * KSB), kp2b = *(const f32x4*)(kspre + kbb + 2 * KSB + 4);
    s16x8 o0, o1, o2;
    float z = 0.f;
    float tb = (float)gl * invL;
#pragma unroll
    for (int e = 0; e < 8; e++) {
      float s2p = b2f((u16)s2v[e]);
      float qv = (e < 4) ? qa[e] : qbv[e - 4];
      float f = qv > 0.f ? qv + 1.f : __expf(qv);
      float Qt = s2p * f;
      float tt = tb * osb[j0 + e];
      float s, cc; __sincosf(tt, &s, &cc);
      float v0 = Qt * s * s, v1 = Qt * cc * cc, v2 = -2.f * Qt * s * cc;
      float k0v = (e < 4) ? kp0a[e] : kp0b[e - 4];
      float k1v = (e < 4) ? kp1a[e] : kp1b[e - 4];
      float k2v = (e < 4) ? kp2a[e] : kp2b[e - 4];
      z += v0 * k0v + v1 * k1v + v2 * k2v;
      o0[e] = (short)f2b(v0); o1[e] = (short)f2b(v1); o2[e] = (short)f2b(v2);
    }
    size_t base = ((size_t)nh * Ln + gl) * 128 + j0;
    *(s16x8*)(qb3 + base)            = o0;
    *(s16x8*)(qb3 + base + NHLD)     = o1;
    *(s16x8*)(qb3 + base + 2 * NHLD) = o2;
    z += __shfl_xor(z, 1); z += __shfl_xor(z, 2);
    z += __shfl_xor(z, 4); z += __shfl_xor(z, 8);
    if (nl == 0) zintg[(size_t)nh * Ln + gl] = z;
  }
}

// ---------------- P3: octet-XOR-swizzled stride-128 tiles, A-fragments hoisted pre-barrier.
// (R11 verbatim)
__global__ __launch_bounds__(512, 4) void p3(const u16* __restrict__ qb3, const u16* __restrict__ kb3,
                                             const u16* __restrict__ vtg, const u16* __restrict__ sct,
                                             const float* __restrict__ zintg, float* __restrict__ outg) {
  __shared__ union {
    struct { alignas(16) u16 T0[128][128]; alignas(16) u16 T1[128][128]; } s;
    alignas(16) float O[128][132];
  } sm;
  int bid = blockIdx.x, t = threadIdx.x;
  int c = bid & 15, h = (bid >> 4) & 7, n = bid >> 7;
  int l0c = c << 7, nh = (n << 3) + h;
  int lane = t & 63, quad = lane >> 4, nl = lane & 15, w = t >> 6;
  f32x4 z4 = {0.f, 0.f, 0.f, 0.f};
  f32x4 accP[8], accO[8];
#pragma unroll
  for (int i = 0; i < 8; i++) { accP[i] = z4; accO[i] = z4; }
  int arow = l0c + (w << 4) + nl;
  for (int b = 0; b < 3; b++) {
    int bnh = b * 32 + nh;
    __syncthreads();
    for (int idx = t; idx < 2048; idx += 512) { // T0 <- Kb chunk [s][i], swizzled octets
      int s = idx >> 4;
      int co = (((idx & 15) ^ (s & 7)) << 3);
      *(s16x8*)&sm.s.T0[s][co] = *(const s16x8*)(kb3 + (((size_t)bnh * Ln + l0c + s) << 7) + ((idx & 15) << 3));
    }
    size_t sbase = ((size_t)(bnh * 16 + c)) << 14;
    for (int idx = t; idx < 2048; idx += 512) { // T1 <- Sprefix^T [j][i], swizzled octets
      int j = idx >> 4;
      int co = (((idx & 15) ^ (j & 7)) << 3);
      *(s16x8*)&sm.s.T1[j][co] = *(const s16x8*)(sct + sbase + ((size_t)j << 7) + ((idx & 15) << 3));
    }
    s16x8 av[4]; // A-fragments issued before the barrier (latency hidden under staging)
#pragma unroll
    for (int ks = 0; ks < 4; ks++)
      av[ks] = *(const s16x8*)(qb3 + (((size_t)bnh * Ln + arow) << 7) + (ks << 5) + (quad << 3));
    __syncthreads();
    for (int ks = 0; ks < 4; ks++) {
      int k0 = (ks << 5) + (quad << 3);
#pragma unroll
      for (int ct = 0; ct < 8; ct++) {
        int r = (ct << 4) + nl;
        int koff = k0 ^ ((r & 7) << 3);       // unswizzle
        s16x8 bv0 = *(const s16x8*)&sm.s.T0[r][koff];
        accP[ct] = __builtin_amdgcn_mfma_f32_16x16x32_bf16(av[ks], bv0, accP[ct], 0, 0, 0);
        s16x8 bv1 = *(const s16x8*)&sm.s.T1[r][koff];
        accO[ct] = __builtin_amdgcn_mfma_f32_16x16x32_bf16(av[ks], bv1, accO[ct], 0, 0, 0);
      }
    }
  }
  __syncthreads();
  // masked P -> T0 as P[l][s] (bf16, swizzled) + register row-sums; stage T1 <- V^T [j][sc]
  float zP[4] = {0.f, 0.f, 0.f, 0.f};
  int lbase = (w << 4) + (quad << 2);
#pragma unroll
  for (int ct = 0; ct < 8; ct++) {
    int ss = (ct << 4) + nl;
#pragma unroll
    for (int r = 0; r < 4; r++) {
      int lr = lbase + r;
      float pv = (ss <= lr) ? accP[ct][r] : 0.f;
      zP[r] += pv;
      sm.s.T0[lr][ss ^ ((lr & 7) << 3)] = f2b(pv);
    }
  }
#pragma unroll
  for (int mteam = 1; mteam <= 8; mteam <<= 1) {
#pragma unroll
    for (int r = 0; r < 4; r++) zP[r] += __shfl_xor(zP[r], mteam);
  }
  size_t vbase = ((size_t)(nh * 16 + c)) << 14;
  for (int idx = t; idx < 2048; idx += 512) { // T1 <- V^T chunk (linear 32KB stream), swizzled
    int j = idx >> 4;
    int co = (((idx & 15) ^ (j & 7)) << 3);
    *(s16x8*)&sm.s.T1[j][co] = *(const s16x8*)(vtg + vbase + ((size_t)idx << 3));
  }
  float zf[4];
#pragma unroll
  for (int r = 0; r < 4; r++)
    zf[r] = zintg[(size_t)nh * Ln + l0c + lbase + r] + zP[r] + 1e-6f;
  __syncthreads();
  // intra: A = masked P (T0 rows l, k=s), B = V^T (T1 rows j, k=s)
  for (int ks = 0; ks < 4; ks++) {
    int k0 = (ks << 5) + (quad << 3);
    int rw = (w << 4) + nl;
    s16x8 pav = *(const s16x8*)&sm.s.T0[rw][k0 ^ ((rw & 7) << 3)];
#pragma unroll
    for (int ct = 0; ct < 8; ct++) {
      int r = (ct << 4) + nl;
      s16x8 vv = *(const s16x8*)&sm.s.T1[r][k0 ^ ((r & 7) << 3)];
      accO[ct] = __builtin_amdgcn_mfma_f32_16x16x32_bf16(pav, vv, accO[ct], 0, 0, 0);
    }
  }
  __syncthreads();
  // divided result -> fp32 LDS overlay (T0/T1 dead now)
#pragma unroll
  for (int ct = 0; ct < 8; ct++) {
    int j = (ct << 4) + nl;
#pragma unroll
    for (int r = 0; r < 4; r++) sm.O[lbase + r][j] = accO[ct][r] / zf[r];
  }
  __syncthreads();
  for (int idx = t; idx < 4096; idx += 512) { // full 512B-row coalesced stores
    int l = idx >> 5, g = (idx & 31) << 2;
    *(f32x4*)(outg + (((size_t)(n * Ln + l0c + l) * 8 + h) << 7) + g) = *(const f32x4*)&sm.O[l][g];
  }
}

extern "C" void kernel_launch(void* const* d_in, const int* in_sizes, int n_in,
                              void* d_out, int out_size, void* d_ws, size_t ws_size,
                              hipStream_t stream) {
  (void)in_sizes; (void)n_in; (void)out_size; (void)ws_size;
  const float* q   = (const float*)d_in[0];
  const float* q2  = (const float*)d_in[1];
  const float* kk  = (const float*)d_in[2];
  const float* vv  = (const float*)d_in[3];
  const float* kl  = (const float*)d_in[4];
  const float* om  = (const float*)d_in[5];
  float* out = (float*)d_out;

  // workspace carve (bf16 region then fp32 region) — ~171 MB
  u16* W     = (u16*)d_ws;
  u16* qb3   = W;                 // 3*NHLD
  u16* kb3   = W + 3 * NHLD;      // 3*NHLD (naturals; k_kvs transposes in-block, L2-hot)
  u16* vt    = W + 6 * NHLD;      // NHLD   (chunk-blocked [nh][c][i][sc])
  u16* sct   = W + 7 * NHLD;      // 3*NHLD (chunk sums -> exclusive prefix, in place)
  u16* wt    = W + 10 * NHLD;     // 131072 (omega^T bf16)
  float* ks  = (float*)(W + 10 * NHLD + 131072); // 196608 f32 (chunk Ksum -> prefix)
  float* osm = ks + 196608;       // 1024 f32
  float* zin = osm + 1024;        // 65536 f32 (Z_inter)

  k_omega <<<8,    256, 0, stream>>>(om, wt, osm);
  k_kvs   <<<512,  512, 0, stream>>>(kk, vv, kl, osm, kb3, vt, sct, ks);
  p1k     <<<48,   256, 0, stream>>>(ks);
  kqm     <<<1792, 256, 0, stream>>>(q2, q, wt, osm, ks, qb3, zin, sct);
  p3      <<<512,  512, 0, stream>>>(qb3, kb3, vt, sct, zin, out);
}